// Round 10
// baseline (478.115 us; speedup 1.0000x reference)
//
#include <hip/hip_runtime.h>
#include <math.h>

#define D_ 512
#define M_ 256
#define T_ 128
#define B_ 8
#define TOPK_ 8
#define NH_ 2
#define BT_ (B_*T_)

__device__ __forceinline__ float wred(float v){
#pragma unroll
  for (int m = 1; m < 64; m <<= 1) v += __shfl_xor(v, m, 64);
  return v;
}
__device__ __forceinline__ float4 ld4(const float* p){ return *(const float4*)p; }
__device__ __forceinline__ void st4(float* p, float4 v){ *(float4*)p = v; }
__device__ __forceinline__ float dot4(float4 a, float4 b){
  return a.x*b.x + a.y*b.y + a.z*b.z + a.w*b.w;
}
__device__ __forceinline__ float4 scl4(float4 a, float s){
  a.x*=s; a.y*=s; a.z*=s; a.w*=s; return a;
}

// DPP wave64 sum (VALU-pipe only, no DS traffic).
template<int CTRL>
__device__ __forceinline__ float dpp_add(float x){
  int y = __builtin_amdgcn_update_dpp(0, __float_as_int(x), CTRL, 0xf, 0xf, true);
  return x + __int_as_float(y);
}
__device__ __forceinline__ float wredd(float x){
  x = dpp_add<0x111>(x);   // row_shr:1
  x = dpp_add<0x112>(x);   // row_shr:2
  x = dpp_add<0x114>(x);   // row_shr:4
  x = dpp_add<0x118>(x);   // row_shr:8
  x = dpp_add<0x142>(x);   // row_bcast:15
  x = dpp_add<0x143>(x);   // row_bcast:31
  return __int_as_float(__builtin_amdgcn_readlane(__float_as_int(x), 63));
}

// ---------------------------------------------------------------------------
// A1: addresses + parallel top-8. meta[bt][r] = {widx, ww, dec, ridx}.
// ---------------------------------------------------------------------------
__global__ __launch_bounds__(64) void addr_kernel(
    const float* __restrict__ h, const float* __restrict__ Wk,
    const float* __restrict__ Wq, const float* __restrict__ ltw,
    const float* __restrict__ ltr, const float* __restrict__ gammap,
    float* __restrict__ metab)
{
  const int bt = blockIdx.x;
  const int tid = threadIdx.x;
  __shared__ float p_s[64];

  const float* hrow = h + (size_t)bt*D_;
  const float* wrow = (tid < 32) ? (Wk + (size_t)tid*D_)
                                 : (Wq + (size_t)(tid-32)*D_);
  float dot = 0.f;
  for (int d = 0; d < D_; d += 4){
    float4 hv = ld4(&hrow[d]); float4 wv = ld4(&wrow[d]);
    dot += hv.x*wv.x + hv.y*wv.y + hv.z*wv.z + hv.w*wv.w;
  }
  float tau = (tid < 32) ? expf(ltw[0]) : expf(ltr[0]);
  float mx = dot;
#pragma unroll
  for (int m = 1; m < 16; m <<= 1) mx = fmaxf(mx, __shfl_xor(mx, m, 64));
  float e = expf((dot - mx)/tau);
  float sm = e;
#pragma unroll
  for (int m = 1; m < 16; m <<= 1) sm += __shfl_xor(sm, m, 64);
  p_s[tid] = e / sm;
  __syncthreads();

  const int half = tid >> 5;
  const int l = tid & 31;
  const int g0 = half*32, g1 = half*32 + 16;
  float av[8];
#pragma unroll
  for (int k = 0; k < 8; ++k){
    int x = l*8 + k;
    av[k] = p_s[g0 + (x>>4)] * p_s[g1 + (x&15)];
  }
  const float sp = log1pf(expf(gammap[0]));
  for (int r = 0; r < TOPK_; ++r){
    float bv = -1.f; int bi = 0;
#pragma unroll
    for (int k = 0; k < 8; ++k){ if (av[k] > bv){ bv = av[k]; bi = l*8+k; } }
#pragma unroll
    for (int m = 1; m < 32; m <<= 1){
      float ov = __shfl_xor(bv, m, 64); int oi = __shfl_xor(bi, m, 64);
      if (ov > bv || (ov == bv && oi < bi)){ bv = ov; bi = oi; }
    }
    if ((bi >> 3) == l) av[bi & 7] = -2.f;
    float* mp = metab + (size_t)(bt*TOPK_ + r)*4;
    if (tid == 0){
      mp[0] = __int_as_float(bi); mp[1] = bv; mp[2] = powf(1.f - bv, sp);
    }
    if (tid == 32) mp[3] = __int_as_float(bi);
  }
}

// ---------------------------------------------------------------------------
// A2 (+A1b fused): fp32 NT GEMM, 128x128 tile, 8x8 micro-tile (half the DS
// traffic per FMA vs 64x64/4x4), double-buffered LDS. grid (4,8,7);
// z==6 / x==0 blocks run the z-recurrence scan concurrently.
// ---------------------------------------------------------------------------
struct GemmPtrs { const float* W[6]; float* C[6]; };

__global__ __launch_bounds__(256) void gemm_nt(
    const float* __restrict__ A, GemmPtrs p,
    const float* __restrict__ zK0, const float* __restrict__ zV0,
    const float* __restrict__ metab, float2* __restrict__ zr,
    float* __restrict__ o_zK, float* __restrict__ o_zV)
{
  if (blockIdx.z == 6){
    if (blockIdx.x != 0) return;
    const int b = blockIdx.y;
    const int m = threadIdx.x;
    const float4* mb = (const float4*)metab + (size_t)b*T_*TOPK_;
    float zk = zK0[b*M_+m], zv = zV0[b*M_+m];
    float4 cur[TOPK_];
#pragma unroll
    for (int i = 0; i < TOPK_; ++i) cur[i] = mb[i];
    for (int t = 0; t < T_; ++t){
      const float4* src = mb + ((t+1 < T_) ? (t+1)*TOPK_ : t*TOPK_);
      float4 nxt[TOPK_];
#pragma unroll
      for (int i = 0; i < TOPK_; ++i) nxt[i] = src[i];
#pragma unroll
      for (int i = 0; i < TOPK_; ++i){
        bool hit = (m == __float_as_int(cur[i].x));
        float nzk = cur[i].z*zk + cur[i].y;
        float nzv = cur[i].z*zv + cur[i].y;
        zk = hit ? nzk : zk;
        zv = hit ? nzv : zv;
      }
#pragma unroll
      for (int i = 0; i < TOPK_; ++i){
        if (m == __float_as_int(cur[i].w))
          zr[(size_t)(b*T_+t)*TOPK_+i] = make_float2(1.0f/zk, 1.0f/zv);
      }
#pragma unroll
      for (int i = 0; i < TOPK_; ++i) cur[i] = nxt[i];
    }
    o_zK[b*M_+m] = zk; o_zV[b*M_+m] = zv;
    return;
  }

  const float* W = p.W[blockIdx.z];
  float* C = p.C[blockIdx.z];
  const int n0 = blockIdx.x * 128;
  const int m0 = blockIdx.y * 128;
  const int tid = threadIdx.x;
  __shared__ __align__(16) float As[2][16][132];
  __shared__ __align__(16) float Bs[2][16][132];
  const int r   = tid >> 1;
  const int c8  = (tid & 1) << 3;
  const int tx8 = (tid & 15) << 3;
  const int ty8 = (tid >> 4) << 3;
  float acc[8][8] = {{0.f}};

  {
    float4 a0 = ld4(&A[(size_t)(m0+r)*512 + c8]);
    float4 a1 = ld4(&A[(size_t)(m0+r)*512 + c8 + 4]);
    float4 w0 = ld4(&W[(size_t)(n0+r)*512 + c8]);
    float4 w1 = ld4(&W[(size_t)(n0+r)*512 + c8 + 4]);
    As[0][c8+0][r]=a0.x; As[0][c8+1][r]=a0.y; As[0][c8+2][r]=a0.z; As[0][c8+3][r]=a0.w;
    As[0][c8+4][r]=a1.x; As[0][c8+5][r]=a1.y; As[0][c8+6][r]=a1.z; As[0][c8+7][r]=a1.w;
    Bs[0][c8+0][r]=w0.x; Bs[0][c8+1][r]=w0.y; Bs[0][c8+2][r]=w0.z; Bs[0][c8+3][r]=w0.w;
    Bs[0][c8+4][r]=w1.x; Bs[0][c8+5][r]=w1.y; Bs[0][c8+6][r]=w1.z; Bs[0][c8+7][r]=w1.w;
  }
  __syncthreads();

  for (int kc = 0, buf = 0; kc < 512; kc += 16, buf ^= 1){
    float4 a0, a1, w0, w1;
    const bool more = (kc + 16 < 512);
    if (more){
      a0 = ld4(&A[(size_t)(m0+r)*512 + kc + 16 + c8]);
      a1 = ld4(&A[(size_t)(m0+r)*512 + kc + 16 + c8 + 4]);
      w0 = ld4(&W[(size_t)(n0+r)*512 + kc + 16 + c8]);
      w1 = ld4(&W[(size_t)(n0+r)*512 + kc + 16 + c8 + 4]);
    }
#pragma unroll
    for (int k = 0; k < 16; ++k){
      float4 xa = ld4(&As[buf][k][ty8]);
      float4 xb = ld4(&As[buf][k][ty8+4]);
      float4 yb0 = ld4(&Bs[buf][k][tx8]);
      float4 yb1 = ld4(&Bs[buf][k][tx8+4]);
      float a8[8] = {xa.x,xa.y,xa.z,xa.w,xb.x,xb.y,xb.z,xb.w};
      float b8[8] = {yb0.x,yb0.y,yb0.z,yb0.w,yb1.x,yb1.y,yb1.z,yb1.w};
#pragma unroll
      for (int i = 0; i < 8; ++i)
#pragma unroll
        for (int j = 0; j < 8; ++j) acc[i][j] += a8[i]*b8[j];
    }
    if (more){
      int nb = buf ^ 1;
      As[nb][c8+0][r]=a0.x; As[nb][c8+1][r]=a0.y; As[nb][c8+2][r]=a0.z; As[nb][c8+3][r]=a0.w;
      As[nb][c8+4][r]=a1.x; As[nb][c8+5][r]=a1.y; As[nb][c8+6][r]=a1.z; As[nb][c8+7][r]=a1.w;
      Bs[nb][c8+0][r]=w0.x; Bs[nb][c8+1][r]=w0.y; Bs[nb][c8+2][r]=w0.z; Bs[nb][c8+3][r]=w0.w;
      Bs[nb][c8+4][r]=w1.x; Bs[nb][c8+5][r]=w1.y; Bs[nb][c8+6][r]=w1.z; Bs[nb][c8+7][r]=w1.w;
      __syncthreads();
    }
  }
#pragma unroll
  for (int i = 0; i < 8; ++i){
    float4 c0; c0.x=acc[i][0]; c0.y=acc[i][1]; c0.z=acc[i][2]; c0.w=acc[i][3];
    float4 c1; c1.x=acc[i][4]; c1.y=acc[i][5]; c1.z=acc[i][6]; c1.w=acc[i][7];
    st4(&C[(size_t)(m0+ty8+i)*512 + n0 + tx8], c0);
    st4(&C[(size_t)(m0+ty8+i)*512 + n0 + tx8 + 4], c1);
  }
}

// ---------------------------------------------------------------------------
// C: fused out = sigmoid(h@Wg.T) * (rdo@Wo.T). 128x64 tile, 8x4 dual acc.
// ---------------------------------------------------------------------------
__global__ __launch_bounds__(256) void gemm_out(
    const float* __restrict__ h, const float* __restrict__ rdo,
    const float* __restrict__ Wg, const float* __restrict__ Wo,
    float* __restrict__ C)
{
  const int n0 = blockIdx.x * 64;
  const int m0 = blockIdx.y * 128;
  const int tid = threadIdx.x;
  __shared__ __align__(16) float Ag[16][132];
  __shared__ __align__(16) float Ao[16][132];
  __shared__ __align__(16) float Bg[16][68];
  __shared__ __align__(16) float Bo[16][68];
  const int r   = tid >> 1;
  const int c8  = (tid & 1) << 3;
  const int r2  = tid >> 2;
  const int c4b = (tid & 3) << 2;
  const int tx4 = (tid & 15) << 2;
  const int ty8 = (tid >> 4) << 3;
  float accg[8][4] = {{0.f}};
  float acco[8][4] = {{0.f}};

  for (int kc = 0; kc < 512; kc += 16){
    float4 a0 = ld4(&h  [(size_t)(m0+r)*512 + kc + c8]);
    float4 a1 = ld4(&h  [(size_t)(m0+r)*512 + kc + c8 + 4]);
    float4 o0 = ld4(&rdo[(size_t)(m0+r)*512 + kc + c8]);
    float4 o1 = ld4(&rdo[(size_t)(m0+r)*512 + kc + c8 + 4]);
    float4 g0 = ld4(&Wg [(size_t)(n0+r2)*512 + kc + c4b]);
    float4 w0 = ld4(&Wo [(size_t)(n0+r2)*512 + kc + c4b]);
    __syncthreads();
    Ag[c8+0][r]=a0.x; Ag[c8+1][r]=a0.y; Ag[c8+2][r]=a0.z; Ag[c8+3][r]=a0.w;
    Ag[c8+4][r]=a1.x; Ag[c8+5][r]=a1.y; Ag[c8+6][r]=a1.z; Ag[c8+7][r]=a1.w;
    Ao[c8+0][r]=o0.x; Ao[c8+1][r]=o0.y; Ao[c8+2][r]=o0.z; Ao[c8+3][r]=o0.w;
    Ao[c8+4][r]=o1.x; Ao[c8+5][r]=o1.y; Ao[c8+6][r]=o1.z; Ao[c8+7][r]=o1.w;
    Bg[c4b+0][r2]=g0.x; Bg[c4b+1][r2]=g0.y; Bg[c4b+2][r2]=g0.z; Bg[c4b+3][r2]=g0.w;
    Bo[c4b+0][r2]=w0.x; Bo[c4b+1][r2]=w0.y; Bo[c4b+2][r2]=w0.z; Bo[c4b+3][r2]=w0.w;
    __syncthreads();
#pragma unroll
    for (int k = 0; k < 16; ++k){
      float4 xg = ld4(&Ag[k][ty8]);
      float4 yg = ld4(&Ag[k][ty8+4]);
      float4 xo = ld4(&Ao[k][ty8]);
      float4 yo = ld4(&Ao[k][ty8+4]);
      float4 bg = ld4(&Bg[k][tx4]);
      float4 bo = ld4(&Bo[k][tx4]);
      float ag8[8] = {xg.x,xg.y,xg.z,xg.w,yg.x,yg.y,yg.z,yg.w};
      float ao8[8] = {xo.x,xo.y,xo.z,xo.w,yo.x,yo.y,yo.z,yo.w};
      float bg4[4] = {bg.x,bg.y,bg.z,bg.w};
      float bo4[4] = {bo.x,bo.y,bo.z,bo.w};
#pragma unroll
      for (int i = 0; i < 8; ++i)
#pragma unroll
        for (int j = 0; j < 4; ++j){
          accg[i][j] += ag8[i]*bg4[j];
          acco[i][j] += ao8[i]*bo4[j];
        }
    }
  }
#pragma unroll
  for (int i = 0; i < 8; ++i){
    float4 cv;
    cv.x = acco[i][0] / (1.f + expf(-accg[i][0]));
    cv.y = acco[i][1] / (1.f + expf(-accg[i][1]));
    cv.z = acco[i][2] / (1.f + expf(-accg[i][2]));
    cv.w = acco[i][3] / (1.f + expf(-accg[i][3]));
    st4(&C[(size_t)(m0+ty8+i)*512 + n0 + tx4], cv);
  }
}

// ---------------------------------------------------------------------------
// A3: fused per-bt elementwise + cross-head precompute.
// ---------------------------------------------------------------------------
__global__ __launch_bounds__(256) void ew2_kernel(
    float* __restrict__ khat, float* __restrict__ kvk, float* __restrict__ kvv,
    float* __restrict__ pre2, const float* __restrict__ h,
    const float* __restrict__ hh_bw, const float* __restrict__ hh_bb)
{
  const int bt = blockIdx.x;
  const int tid = threadIdx.x;
  const int wid = tid >> 6, lane = tid & 63;
  float* k0p  = khat + (size_t)bt*D_;
  float* k1p  = khat + (size_t)BT_*D_ + (size_t)bt*D_;
  float* vk0p = kvk  + (size_t)bt*D_;
  float* vk1p = kvk  + (size_t)BT_*D_ + (size_t)bt*D_;
  float* vv0p = kvv  + (size_t)bt*D_;
  float* vv1p = kvv  + (size_t)BT_*D_ + (size_t)bt*D_;
  const float* hp  = h + (size_t)bt*D_;

  float s0[2], s1[2];
  float n0 = 0.f, n1 = 0.f, bd0 = 0.f, bd1 = 0.f;
#pragma unroll
  for (int q = 0; q < 2; ++q){
    int d = tid + q*256;
    float x0 = k0p[d], x1 = k1p[d], hv = hp[d];
    float v0 = x0 / (1.f + expf(-x0));
    float v1 = x1 / (1.f + expf(-x1));
    s0[q] = v0; s1[q] = v1;
    n0 += v0*v0; n1 += v1*v1;
    bd0 += hv*hh_bw[d]; bd1 += hv*hh_bw[D_ + d];
  }
  __shared__ float4 rb[4];
  float4 acc = make_float4(wred(n0), wred(n1), wred(bd0), wred(bd1));
  if (lane == 0) rb[wid] = acc;
  __syncthreads();
  float4 t0 = rb[0], t1 = rb[1], t2 = rb[2], t3 = rb[3];
  n0 = t0.x+t1.x+t2.x+t3.x; n1 = t0.y+t1.y+t2.y+t3.y;
  bd0 = t0.z+t1.z+t2.z+t3.z; bd1 = t0.w+t1.w+t2.w+t3.w;
  float inv0 = 1.f / fmaxf(sqrtf(n0), 1e-12f);
  float inv1 = 1.f / fmaxf(sqrtf(n1), 1e-12f);
  float be0 = 2.f / (1.f + expf(-(bd0 + hh_bb[0])));
  float be1 = 2.f / (1.f + expf(-(bd1 + hh_bb[1])));

  float c01 = 0.f, dK = 0.f, dV = 0.f;
#pragma unroll
  for (int q = 0; q < 2; ++q){
    int d = tid + q*256;
    float kh0 = s0[q]*inv0, kh1 = s1[q]*inv1;
    float u0K = s0[q]*vk0p[d], u1K = s1[q]*vk1p[d];
    float u0V = s0[q]*vv0p[d], u1V = s1[q]*vv1p[d];
    k0p[d] = kh0; k1p[d] = kh1;
    vk0p[d] = be0*u0K + be1*u1K;
    vv0p[d] = be0*u0V + be1*u1V;
    c01 += kh1*kh0; dK += kh1*u0K; dV += kh1*u0V;
  }
  __syncthreads();
  float4 acc2 = make_float4(wred(c01), wred(dK), wred(dV), 0.f);
  if (lane == 0) rb[wid] = acc2;
  __syncthreads();
  if (tid == 0){
    float4 a = rb[0], b = rb[1], c = rb[2], d = rb[3];
    pre2[(size_t)bt*8+0] = a.x+b.x+c.x+d.x;
    pre2[(size_t)bt*8+1] = a.y+b.y+c.y+d.y;
    pre2[(size_t)bt*8+2] = a.z+b.z+c.z+d.z;
    pre2[(size_t)bt*8+3] = be0;
    pre2[(size_t)bt*8+4] = be1;
  }
}

// ---------------------------------------------------------------------------
// B: sequential scan v9 — one barrier/step; register staging; wave-uniform
// slot indices moved to SGPRs (readfirstlane) for scalar addressing.
// ---------------------------------------------------------------------------
__global__ __launch_bounds__(512) void scan_kernel(
    float* __restrict__ Ks, float* __restrict__ Vs,
    const float* __restrict__ khat, const float* __restrict__ ucKp,
    const float* __restrict__ ucVp, const float* __restrict__ pre2,
    const float* __restrict__ metab, const float2* __restrict__ zr,
    const float* __restrict__ h, float* __restrict__ readout,
    float* __restrict__ o_widx, float* __restrict__ o_ridx)
{
  __shared__ __align__(16) float Vr_s[2][TOPK_][D_];
  __shared__ float2 rel2_s[2][TOPK_];

  const int b = blockIdx.x;
  const int tid = threadIdx.x;
  const int s = tid >> 6, lane = tid & 63;
  const int l4 = lane * 4;
  const float scale = 0.044194173824159216f;   // 1/sqrt(512)

  float* Ksb = Ks + (size_t)b*M_*D_;
  float* Vsb = Vs + (size_t)b*M_*D_;
  const float* kh0p = khat;
  const float* kh1p = khat + (size_t)BT_*D_;
  const float4* mb = (const float4*)metab;

  // ---- prologue ----
  const int bt0 = b*T_;
  size_t o0 = (size_t)bt0*D_ + l4;
  float4 c_kh0a = ld4(kh0p+o0), c_kh0b = ld4(kh0p+o0+256);
  float4 c_kh1a = ld4(kh1p+o0), c_kh1b = ld4(kh1p+o0+256);
  float4 c_uKa  = ld4(ucKp+o0), c_uKb  = ld4(ucKp+o0+256);
  float4 c_uVa  = ld4(ucVp+o0), c_uVb  = ld4(ucVp+o0+256);

  float4 me   = mb[bt0*TOPK_ + s];
  float4 me_n = mb[(bt0+1)*TOPK_ + s];
  float4 pm   = ld4(&pre2[(size_t)bt0*8]);
  float  be1v = pre2[(size_t)bt0*8+4];
  float4 pm_n = ld4(&pre2[(size_t)(bt0+1)*8]);
  float  be1_n= pre2[(size_t)(bt0+1)*8+4];
  float2 zr2   = zr[(size_t)bt0*TOPK_ + s];
  float2 zr2_n = zr[(size_t)(bt0+1)*TOPK_ + s];

  {
    int mi0 = __builtin_amdgcn_readfirstlane(__float_as_int(me.x));
    float4 K0p = ld4(&Ksb[(size_t)mi0*D_ + l4]);
    float4 K1p = ld4(&Ksb[(size_t)mi0*D_ + 256 + l4]);
    float4 V0p = ld4(&Vsb[(size_t)mi0*D_ + l4]);
    float4 V1p = ld4(&Vsb[(size_t)mi0*D_ + 256 + l4]);
    // fallthrough into the loop with these as pipeline regs
    float4 K0=K0p, K1=K1p, V0=V0p, V1=V1p;

#pragma unroll 2
    for (int t = 0; t < T_; ++t){
      const int bt = b*T_ + t;
      const float dec = me.z;
      const int ri = __builtin_amdgcn_readfirstlane(__float_as_int(me.w));
      const int mi = __builtin_amdgcn_readfirstlane(__float_as_int(me.x));

      // ---------------- A(t) ----------------
      const int btn  = (t+1 < T_) ? bt+1 : bt;
      const int btnn = (t+2 < T_) ? bt+2 : b*T_+T_-1;
      size_t on = (size_t)btn*D_ + l4;
      float4 n_kh0a = ld4(kh0p+on), n_kh0b = ld4(kh0p+on+256);
      float4 n_kh1a = ld4(kh1p+on), n_kh1b = ld4(kh1p+on+256);
      float4 n_uKa  = ld4(ucKp+on), n_uKb  = ld4(ucKp+on+256);
      float4 n_uVa  = ld4(ucVp+on), n_uVb  = ld4(ucVp+on+256);
      float4 HTa = ld4(h + (size_t)bt*D_ + l4);
      float4 HTb = ld4(h + (size_t)bt*D_ + 256 + l4);
      float4 me_nn = mb[btnn*TOPK_ + s];
      float4 pm_nn = ld4(&pre2[(size_t)btnn*8]);
      float  be1nn = pre2[(size_t)btnn*8+4];
      float2 zr2nn = zr[(size_t)btnn*TOPK_ + s];

      // fused 2-head state update
      K0 = scl4(K0,dec); K1 = scl4(K1,dec);
      V0 = scl4(V0,dec); V1 = scl4(V1,dec);
      float aK = wredd(dot4(K0,c_kh0a) + dot4(K1,c_kh0b));
      float bK = wredd(dot4(K0,c_kh1a) + dot4(K1,c_kh1b));
      float aV = wredd(dot4(V0,c_kh0a) + dot4(V1,c_kh0b));
      float bV = wredd(dot4(V0,c_kh1a) + dot4(V1,c_kh1b));
      float p0K = pm.w*aK, p1K = be1v*(bK + pm.w*(pm.y - aK*pm.x));
      float p0V = pm.w*aV, p1V = be1v*(bV + pm.w*(pm.z - aV*pm.x));
      K0.x += c_uKa.x - p0K*c_kh0a.x - p1K*c_kh1a.x;
      K0.y += c_uKa.y - p0K*c_kh0a.y - p1K*c_kh1a.y;
      K0.z += c_uKa.z - p0K*c_kh0a.z - p1K*c_kh1a.z;
      K0.w += c_uKa.w - p0K*c_kh0a.w - p1K*c_kh1a.w;
      K1.x += c_uKb.x - p0K*c_kh0b.x - p1K*c_kh1b.x;
      K1.y += c_uKb.y - p0K*c_kh0b.y - p1K*c_kh1b.y;
      K1.z += c_uKb.z - p0K*c_kh0b.z - p1K*c_kh1b.z;
      K1.w += c_uKb.w - p0K*c_kh0b.w - p1K*c_kh1b.w;
      V0.x += c_uVa.x - p0V*c_kh0a.x - p1V*c_kh1a.x;
      V0.y += c_uVa.y - p0V*c_kh0a.y - p1V*c_kh1a.y;
      V0.z += c_uVa.z - p0V*c_kh0a.z - p1V*c_kh1a.z;
      V0.w += c_uVa.w - p0V*c_kh0a.w - p1V*c_kh1a.w;
      V1.x += c_uVb.x - p0V*c_kh0b.x - p1V*c_kh1b.x;
      V1.y += c_uVb.y - p0V*c_kh0b.y - p1V*c_kh1b.y;
      V1.z += c_uVb.z - p0V*c_kh0b.z - p1V*c_kh1b.z;
      V1.w += c_uVb.w - p0V*c_kh0b.w - p1V*c_kh1b.w;

      st4(&Ksb[(size_t)mi*D_ + l4], K0); st4(&Ksb[(size_t)mi*D_ + 256 + l4], K1);
      st4(&Vsb[(size_t)mi*D_ + l4], V0); st4(&Vsb[(size_t)mi*D_ + 256 + l4], V1);

      __syncthreads();   // THE barrier: scatters drained & visible

      // ---------------- B(t) ----------------
      float4 RK0 = ld4(&Ksb[(size_t)ri*D_ + l4]);
      float4 RK1 = ld4(&Ksb[(size_t)ri*D_ + 256 + l4]);
      float4 RV0 = ld4(&Vsb[(size_t)ri*D_ + l4]);
      float4 RV1 = ld4(&Vsb[(size_t)ri*D_ + 256 + l4]);
      const int mi_n = __builtin_amdgcn_readfirstlane(__float_as_int(me_n.x));
      float4 nK0 = ld4(&Ksb[(size_t)mi_n*D_ + l4]);
      float4 nK1 = ld4(&Ksb[(size_t)mi_n*D_ + 256 + l4]);
      float4 nV0 = ld4(&Vsb[(size_t)mi_n*D_ + l4]);
      float4 nV1 = ld4(&Vsb[(size_t)mi_n*D_ + 256 + l4]);

      if (t > 0){
        const int pp = (t-1) & 1;
        float2 rz[TOPK_];
#pragma unroll
        for (int i = 0; i < TOPK_; ++i) rz[i] = rel2_s[pp][i];
        float mx = rz[0].x;
#pragma unroll
        for (int i = 1; i < TOPK_; ++i) mx = fmaxf(mx, rz[i].x);
        float smm = 0.f, r = 0.f;
#pragma unroll
        for (int i = 0; i < TOPK_; ++i){
          float ev = __expf(rz[i].x - mx); smm += ev;
          r += ev * rz[i].y * Vr_s[pp][i][tid];
        }
        readout[(size_t)(bt-1)*D_ + tid] = r * __builtin_amdgcn_rcpf(smm);
      }

      float dt = wredd(dot4(RK0,HTa) + dot4(RK1,HTb));
      if (lane == 0)
        rel2_s[t&1][s] = make_float2(dt * scale * zr2.x, zr2.y);
      st4(&Vr_s[t&1][s][l4], RV0); st4(&Vr_s[t&1][s][256+l4], RV1);

      // rotate pipeline
      K0=nK0; K1=nK1; V0=nV0; V1=nV1;
      me=me_n; pm=pm_n; be1v=be1_n; zr2=zr2_n;
      me_n=me_nn; pm_n=pm_nn; be1_n=be1nn; zr2_n=zr2nn;
      c_kh0a=n_kh0a; c_kh0b=n_kh0b; c_kh1a=n_kh1a; c_kh1b=n_kh1b;
      c_uKa=n_uKa; c_uKb=n_uKb; c_uVa=n_uVa; c_uVb=n_uVb;
    }
  }

  // ---- epilogue: readout(T-1) ----
  __syncthreads();
  {
    const int btL = b*T_ + T_ - 1;
    const int pp = (T_-1) & 1;
    float2 rz[TOPK_];
#pragma unroll
    for (int i = 0; i < TOPK_; ++i) rz[i] = rel2_s[pp][i];
    float mx = rz[0].x;
#pragma unroll
    for (int i = 1; i < TOPK_; ++i) mx = fmaxf(mx, rz[i].x);
    float smm = 0.f, r = 0.f;
#pragma unroll
    for (int i = 0; i < TOPK_; ++i){
      float ev = __expf(rz[i].x - mx); smm += ev;
      r += ev * rz[i].y * Vr_s[pp][i][tid];
    }
    readout[(size_t)btL*D_ + tid] = r * __builtin_amdgcn_rcpf(smm);

    if (tid < TOPK_){
      float4 m = mb[btL*TOPK_ + tid];
      o_widx[b*TOPK_+tid] = (float)__float_as_int(m.x);
      o_ridx[b*TOPK_+tid] = (float)__float_as_int(m.w);
    }
  }
}

// ---------------------------------------------------------------------------
extern "C" void kernel_launch(void* const* d_in, const int* in_sizes, int n_in,
                              void* d_out, int out_size, void* d_ws, size_t ws_size,
                              hipStream_t stream)
{
  (void)in_sizes; (void)n_in; (void)out_size; (void)ws_size;
  const float* h       = (const float*)d_in[0];
  const float* K_slots = (const float*)d_in[1];
  const float* V_slots = (const float*)d_in[2];
  const float* z_K     = (const float*)d_in[3];
  const float* z_V     = (const float*)d_in[4];
  const float* W_k     = (const float*)d_in[5];
  const float* W_q     = (const float*)d_in[6];
  const float* ltw     = (const float*)d_in[7];
  const float* ltr     = (const float*)d_in[8];
  const float* hh_k    = (const float*)d_in[9];
  const float* hh_vk   = (const float*)d_in[10];
  const float* hh_vv   = (const float*)d_in[11];
  const float* hh_bw   = (const float*)d_in[12];
  const float* hh_bb   = (const float*)d_in[13];
  const float* gamma   = (const float*)d_in[14];
  const float* W_out   = (const float*)d_in[15];
  const float* W_gate  = (const float*)d_in[16];

  float* out    = (float*)d_out;
  float* o_outs = out;                 // (B,T,D)   524288
  float* o_Ks   = out + 524288;        // (B,M,D)  1048576
  float* o_Vs   = out + 1572864;       // (B,M,D)  1048576
  float* o_zK   = out + 2621440;       // (B,M)       2048
  float* o_zV   = out + 2623488;       // (B,M)       2048
  float* o_widx = out + 2625536;       // (B,8)         64
  float* o_ridx = out + 2625600;       // (B,8)         64

  float* ws    = (float*)d_ws;
  float* khat  = ws;                          // 2 * BT * D
  float* kvk   = ws + 2*(size_t)BT_*D_;       // 2 * BT * D
  float* kvv   = kvk + 2*(size_t)BT_*D_;      // 2 * BT * D
  float* rdo   = kvv + 2*(size_t)BT_*D_;      // BT * D
  float* metab = rdo + (size_t)BT_*D_;        // BT * 8 * 4
  float* pre2  = metab + (size_t)BT_*TOPK_*4; // BT * 8
  float2* zrb  = (float2*)(pre2 + (size_t)BT_*8); // BT * 8 float2

  (void)hipMemcpyAsync(o_Ks, K_slots, sizeof(float)*(size_t)B_*M_*D_,
                       hipMemcpyDeviceToDevice, stream);
  (void)hipMemcpyAsync(o_Vs, V_slots, sizeof(float)*(size_t)B_*M_*D_,
                       hipMemcpyDeviceToDevice, stream);

  addr_kernel<<<BT_, 64, 0, stream>>>(h, W_k, W_q, ltw, ltr, gamma, metab);

  GemmPtrs p{};
  p.W[0] = hh_k;           p.C[0] = khat;
  p.W[1] = hh_k + 262144;  p.C[1] = khat + (size_t)BT_*D_;
  p.W[2] = hh_vk;          p.C[2] = kvk;
  p.W[3] = hh_vk + 262144; p.C[3] = kvk + (size_t)BT_*D_;
  p.W[4] = hh_vv;          p.C[4] = kvv;
  p.W[5] = hh_vv + 262144; p.C[5] = kvv + (size_t)BT_*D_;
  // grid.z==6 slice (blockIdx.x==0, y = batch) runs the fused z-scan
  gemm_nt<<<dim3(4,8,7), 256, 0, stream>>>(h, p, z_K, z_V, metab, zrb,
                                           o_zK, o_zV);

  ew2_kernel<<<BT_, 256, 0, stream>>>(khat, kvk, kvv, pre2, h, hh_bw, hh_bb);

  scan_kernel<<<B_, 512, 0, stream>>>(o_Ks, o_Vs, khat, kvk, kvv,
                                      pre2, metab, zrb, h, rdo,
                                      o_widx, o_ridx);

  gemm_out<<<dim3(8,8), 256, 0, stream>>>(h, rdo, W_gate, W_out, o_outs);
}